// Round 9
// baseline (372.897 us; speedup 1.0000x reference)
//
#include <hip/hip_runtime.h>
#include <hip/hip_bf16.h>
#include <stdint.h>

#define D_MODEL 1024
#define NH      16
#define HD      64
#define B_SZ    4
#define SEQ     2048
#define M_TOT   (B_SZ*SEQ)
#define LOG2E_O8 0.18033688011112042f   // log2(e)/8

typedef __bf16 bf16;
typedef bf16  bf16x8 __attribute__((ext_vector_type(8)));
typedef bf16  bf16x4 __attribute__((ext_vector_type(4)));
typedef float f32x4  __attribute__((ext_vector_type(4)));

static __device__ __forceinline__ f32x4 mfma16(bf16x8 a, bf16x8 b, f32x4 c) {
  return __builtin_amdgcn_mfma_f32_16x16x32_bf16(a, b, c, 0, 0, 0);
}

// async global->LDS, 16B per lane; LDS dest = wave-uniform base + lane*16
static __device__ __forceinline__ void gl2lds(const void* g, void* l) {
  __builtin_amdgcn_global_load_lds(
      (const __attribute__((address_space(1))) unsigned int*)g,
      (__attribute__((address_space(3))) unsigned int*)l,
      16, 0, 0);
}

// raw barrier + counted vmcnt: leaves weight stores in flight (T4)
#define BAR_VM16() do { \
  asm volatile("s_waitcnt vmcnt(16) lgkmcnt(0)" ::: "memory"); \
  __builtin_amdgcn_s_barrier(); \
  __builtin_amdgcn_sched_barrier(0); \
} while (0)

#define BAR_LGKM() do { \
  asm volatile("s_waitcnt lgkmcnt(0)" ::: "memory"); \
  __builtin_amdgcn_s_barrier(); \
  __builtin_amdgcn_sched_barrier(0); \
} while (0)

// -------- transpose+convert 4 weights: W[k][n] f32 -> Wt[n][k] bf16 --------
__global__ __launch_bounds__(256) void k_twt(const float* __restrict__ w0,
                                             const float* __restrict__ w1,
                                             const float* __restrict__ w2,
                                             const float* __restrict__ w3,
                                             bf16* __restrict__ t0,
                                             bf16* __restrict__ t1,
                                             bf16* __restrict__ t2,
                                             bf16* __restrict__ t3) {
  __shared__ bf16 t[64][65];
  int z = blockIdx.z;
  const float* W = z == 0 ? w0 : z == 1 ? w1 : z == 2 ? w2 : w3;
  bf16* Wt = z == 0 ? t0 : z == 1 ? t1 : z == 2 ? t2 : t3;
  int k0 = blockIdx.x * 64, n0 = blockIdx.y * 64;
  int r = threadIdx.x >> 2, c0 = (threadIdx.x & 3) * 16;
  const float* p = W + (size_t)(k0 + r) * D_MODEL + n0 + c0;
#pragma unroll
  for (int e = 0; e < 16; e += 4) {
    float4 v = *(const float4*)(p + e);
    t[r][c0+e+0] = (bf16)v.x; t[r][c0+e+1] = (bf16)v.y;
    t[r][c0+e+2] = (bf16)v.z; t[r][c0+e+3] = (bf16)v.w;
  }
  __syncthreads();
  bf16x8 o0, o1;
#pragma unroll
  for (int e = 0; e < 8; e++) { o0[e] = t[c0+e][r]; o1[e] = t[c0+8+e][r]; }
  bf16* q = Wt + (size_t)(n0 + r) * D_MODEL + k0 + c0;
  *(bf16x8*)q = o0; *(bf16x8*)(q + 8) = o1;
}

// -------- fused QKV projection GEMM, fp32 A reg-staged, B via gl2lds --------
__global__ __launch_bounds__(256) void k_qkv(const float* __restrict__ Aq,
                                             const float* __restrict__ Ak,
                                             const float* __restrict__ Av,
                                             const bf16* __restrict__ Wt3,
                                             const float* __restrict__ bq,
                                             const float* __restrict__ bk,
                                             const float* __restrict__ bv,
                                             bf16* __restrict__ HQ,
                                             bf16* __restrict__ Vt) {
  __shared__ alignas(16) bf16 sA[2][8192];
  __shared__ alignas(16) bf16 sB[2][8192];
  const int tid = threadIdx.x;
  const int lane = tid & 63, wv = tid >> 6;
  const int g = lane >> 4, lr = lane & 15;
  const int wm = wv >> 1, wn = wv & 1;
  const int d = blockIdx.x;
  const int p = (d & 7) * 24 + (d >> 6);      // panel 0..191 (XCD d&7)
  const int seg = p >> 6;
  const int m0 = (p & 63) * 128;
  const int n0 = ((d >> 3) & 7) * 128;

  const float* A = seg == 0 ? Aq : seg == 1 ? Ak : Av;
  const float* bias = seg == 0 ? bq : seg == 1 ? bk : bv;
  const float oscale = seg == 0 ? LOG2E_O8 : 1.0f;

  const float* ap[4]; int adst[4];
#pragma unroll
  for (int i = 0; i < 4; i++) {
    int row = i * 32 + (tid >> 3), col = (tid & 7) * 8;
    ap[i] = A + (size_t)(m0 + row) * D_MODEL + col;
    adst[i] = row * 128 + ((col * 2) ^ ((row & 7) << 4));
  }
  const char* bsrc[4]; int bdst[4];
#pragma unroll
  for (int i = 0; i < 4; i++) {
    int o = i * 4096 + tid * 16;
    int brow = o >> 7, bin = o & 127;
    bsrc[i] = (const char*)Wt3 + (size_t)(seg * 1024 + n0 + brow) * 2048
              + (bin ^ ((brow & 7) << 4));
    bdst[i] = i * 4096 + wv * 1024;
  }
  int fa[4], fb[4], swa[4], swb[4];
#pragma unroll
  for (int i = 0; i < 4; i++) {
    int rowa = wm * 64 + i * 16 + lr;
    int rowb = wn * 64 + i * 16 + lr;
    fa[i] = rowa * 128; swa[i] = (rowa & 7) << 4;
    fb[i] = rowb * 128; swb[i] = (rowb & 7) << 4;
  }
  f32x4 acc[4][4] = {};
  float4 af[4][2];

#pragma unroll
  for (int i = 0; i < 4; i++) gl2lds(bsrc[i], (char*)sB[0] + bdst[i]);
#pragma unroll
  for (int i = 0; i < 4; i++) { af[i][0] = *(const float4*)ap[i]; af[i][1] = *(const float4*)(ap[i] + 4); }
#pragma unroll
  for (int i = 0; i < 4; i++) {
    bf16x8 w8;
#pragma unroll
    for (int e = 0; e < 4; e++) { w8[e] = (bf16)af[i][0][e]; w8[4+e] = (bf16)af[i][1][e]; }
    *(bf16x8*)((char*)sA[0] + adst[i]) = w8;
  }
  __syncthreads();

  int cur = 0;
  for (int kt = 0; kt < 16; ++kt) {
    if (kt < 15) {
#pragma unroll
      for (int i = 0; i < 4; i++)
        gl2lds(bsrc[i] + (kt + 1) * 128, (char*)sB[cur ^ 1] + bdst[i]);
#pragma unroll
      for (int i = 0; i < 4; i++) {
        af[i][0] = *(const float4*)(ap[i] + (kt + 1) * 64);
        af[i][1] = *(const float4*)(ap[i] + (kt + 1) * 64 + 4);
      }
    }
    const char* bA = (const char*)sA[cur];
    const char* bB = (const char*)sB[cur];
#pragma unroll
    for (int c = 0; c < 2; c++) {
      bf16x8 a[4], b[4];
      int off = c * 64 + g * 16;
#pragma unroll
      for (int i = 0; i < 4; i++) {
        a[i] = *(const bf16x8*)(bA + fa[i] + (off ^ swa[i]));
        b[i] = *(const bf16x8*)(bB + fb[i] + (off ^ swb[i]));
      }
#pragma unroll
      for (int mi = 0; mi < 4; mi++)
#pragma unroll
        for (int ni = 0; ni < 4; ni++)
          acc[mi][ni] = mfma16(a[mi], b[ni], acc[mi][ni]);
    }
    if (kt < 15) {
#pragma unroll
      for (int i = 0; i < 4; i++) {
        bf16x8 w8;
#pragma unroll
        for (int e = 0; e < 4; e++) { w8[e] = (bf16)af[i][0][e]; w8[4+e] = (bf16)af[i][1][e]; }
        *(bf16x8*)((char*)sA[cur ^ 1] + adst[i]) = w8;
      }
    }
    __syncthreads();
    cur ^= 1;
  }

  if (seg < 2) {
    bf16* outp = HQ + (size_t)seg * 8388608;
#pragma unroll
    for (int mi = 0; mi < 4; mi++) {
#pragma unroll
      for (int ni = 0; ni < 4; ni++) {
        int n = n0 + wn * 64 + ni * 16 + lr;
        float bvl = bias[n];
        int h = n >> 6, dd = n & 63;
#pragma unroll
        for (int r = 0; r < 4; r++) {
          int m = m0 + wm * 64 + mi * 16 + g * 4 + r;
          int b = m >> 11, q = m & 2047;
          outp[(((size_t)(b * NH + h)) * SEQ + q) * HD + dd] =
              (bf16)((acc[mi][ni][r] + bvl) * oscale);
        }
      }
    }
  } else {
    char* tr = (char*)sA;
#pragma unroll
    for (int mi = 0; mi < 4; mi++) {
#pragma unroll
      for (int ni = 0; ni < 4; ni++) {
        int n_loc = wn * 64 + ni * 16 + lr;
        float bvl = bias[n0 + n_loc];
        bf16x4 pq;
#pragma unroll
        for (int r = 0; r < 4; r++) pq[r] = (bf16)(acc[mi][ni][r] + bvl);
        int m0l = wm * 64 + mi * 16 + g * 4;
        *(bf16x4*)(tr + n_loc * 256 + ((m0l * 2) ^ ((n_loc & 7) << 4))) = pq;
      }
    }
    __syncthreads();
    int n_loc = tid >> 1, mh = (tid & 1) * 64;
    int n_glob = n0 + n_loc;
    int h = n_glob >> 6, dd = n_glob & 63;
    int b = m0 >> 11, q0l = (m0 & 2047) + mh;
    bf16* vp = Vt + ((size_t)(b * NH + h) * HD + dd) * SEQ + q0l;
    int sw = (n_loc & 7) << 4;
#pragma unroll
    for (int c = 0; c < 8; c++) {
      bf16x8 v8 = *(const bf16x8*)(tr + n_loc * 256 + ((mh * 2 + c * 16) ^ sw));
      *(bf16x8*)(vp + c * 8) = v8;
    }
  }
}

// -------- O-projection GEMM: A bf16 via gl2lds, out f32 [M,1024] --------
__global__ __launch_bounds__(256) void k_ogemm(const bf16* __restrict__ A,
                                               const bf16* __restrict__ Bt,
                                               const float* __restrict__ bias,
                                               float* __restrict__ outp) {
  __shared__ alignas(16) bf16 sA[2][8192];
  __shared__ alignas(16) bf16 sB[2][8192];
  const int tid = threadIdx.x;
  const int lane = tid & 63, wv = tid >> 6;
  const int g = lane >> 4, lr = lane & 15;
  const int wm = wv >> 1, wn = wv & 1;
  const int d = blockIdx.x;
  const int m0 = ((d & 7) * 8 + (d >> 6)) * 128;
  const int n0 = ((d >> 3) & 7) * 128;

  const char* asrc[4]; const char* bsrc[4]; int dst[4];
#pragma unroll
  for (int i = 0; i < 4; i++) {
    int o = i * 4096 + tid * 16;
    int row = o >> 7, in = o & 127;
    int cs = in ^ ((row & 7) << 4);
    asrc[i] = (const char*)A  + (size_t)(m0 + row) * 2048 + cs;
    bsrc[i] = (const char*)Bt + (size_t)(n0 + row) * 2048 + cs;
    dst[i] = i * 4096 + wv * 1024;
  }
  int fa[4], fb[4], swa[4], swb[4];
#pragma unroll
  for (int i = 0; i < 4; i++) {
    int rowa = wm * 64 + i * 16 + lr;
    int rowb = wn * 64 + i * 16 + lr;
    fa[i] = rowa * 128; swa[i] = (rowa & 7) << 4;
    fb[i] = rowb * 128; swb[i] = (rowb & 7) << 4;
  }
  f32x4 acc[4][4] = {};
#pragma unroll
  for (int i = 0; i < 4; i++) {
    gl2lds(asrc[i], (char*)sA[0] + dst[i]);
    gl2lds(bsrc[i], (char*)sB[0] + dst[i]);
  }
  __syncthreads();
  int cur = 0;
  for (int kt = 0; kt < 16; ++kt) {
    if (kt < 15) {
#pragma unroll
      for (int i = 0; i < 4; i++) {
        gl2lds(asrc[i] + (kt + 1) * 128, (char*)sA[cur ^ 1] + dst[i]);
        gl2lds(bsrc[i] + (kt + 1) * 128, (char*)sB[cur ^ 1] + dst[i]);
      }
    }
    const char* bA = (const char*)sA[cur];
    const char* bB = (const char*)sB[cur];
#pragma unroll
    for (int c = 0; c < 2; c++) {
      bf16x8 a[4], b[4];
      int off = c * 64 + g * 16;
#pragma unroll
      for (int i = 0; i < 4; i++) {
        a[i] = *(const bf16x8*)(bA + fa[i] + (off ^ swa[i]));
        b[i] = *(const bf16x8*)(bB + fb[i] + (off ^ swb[i]));
      }
#pragma unroll
      for (int mi = 0; mi < 4; mi++)
#pragma unroll
        for (int ni = 0; ni < 4; ni++)
          acc[mi][ni] = mfma16(a[mi], b[ni], acc[mi][ni]);
    }
    __syncthreads();
    cur ^= 1;
  }
#pragma unroll
  for (int mi = 0; mi < 4; mi++) {
#pragma unroll
    for (int ni = 0; ni < 4; ni++) {
      int n = n0 + wn * 64 + ni * 16 + lr;
      float bvl = bias[n];
#pragma unroll
      for (int r = 0; r < 4; r++) {
        int m = m0 + wm * 64 + mi * 16 + g * 4 + r;
        outp[(size_t)m * D_MODEL + n] = acc[mi][ni][r] + bvl;
      }
    }
  }
}

// -------- fused attention: 2-tile pipelined, swapped QK^T (exp2), coalesced NT W --------
// Each block owns TWO adjacent 128-row q-tiles. P0 = denom(T0); P1 = weights/PV(T0)
// merged with denom(T1) — compute rides under the write stream; P2 = weights/PV(T1).
__global__ __launch_bounds__(256) void k_attn(const bf16* __restrict__ Qh,
                                              const bf16* __restrict__ Kh,
                                              const bf16* __restrict__ Vt,
                                              float* __restrict__ Wout,
                                              bf16* __restrict__ O) {
  __shared__ alignas(16) bf16 sK[2][8192];   // [buf][128k][64d], xor-swizzled
  __shared__ alignas(16) bf16 sV[8192];      // [64d][128k],      xor-swizzled
  __shared__ alignas(16) bf16 sP[16384];     // [128q][128k],     xor-swizzled
  const int tid = threadIdx.x, lane = tid & 63, wv = tid >> 6;
  const int g = lane >> 4, lr = lane & 15;
  // 512 blocks = 8 XCD x 64; bh = swzb>>3 keeps each bh's 8 blocks on one XCD
  int swzb = (blockIdx.x & 7) * 64 + (blockIdx.x >> 3);
  const int bh = swzb >> 3;
  const int qt0 = (swzb & 7) * 256;
  const int qw0 = qt0 + wv * 32;
  const int qw1 = qt0 + 128 + wv * 32;

  bf16x8 qb0[2][2], qb1[2][2];
#pragma unroll
  for (int mi = 0; mi < 2; mi++)
#pragma unroll
    for (int c = 0; c < 2; c++) {
      qb0[mi][c] = *(const bf16x8*)(Qh + ((size_t)bh * SEQ + qw0 + mi * 16 + lr) * HD + c * 32 + g * 8);
      qb1[mi][c] = *(const bf16x8*)(Qh + ((size_t)bh * SEQ + qw1 + mi * 16 + lr) * HD + c * 32 + g * 8);
    }

  const char* kbase = (const char*)(Kh + (size_t)bh * SEQ * HD);
  const char* vbase = (const char*)(Vt + (size_t)bh * HD * SEQ);
  const char* ksrc[4]; const char* vsrc[4]; int ldst[4];
#pragma unroll
  for (int i = 0; i < 4; i++) {
    int o = i * 4096 + tid * 16;
    int kr = o >> 7, kin = o & 127;
    ksrc[i] = kbase + (size_t)kr * 128 + (kin ^ ((kr & 7) << 4));
    int dr = o >> 8, vin = o & 255;
    vsrc[i] = vbase + (size_t)dr * 4096 + (vin ^ ((dr & 7) << 4));
    ldst[i] = i * 4096 + wv * 1024;
  }

#pragma unroll
  for (int i = 0; i < 4; i++) gl2lds(ksrc[i], (char*)sK + ldst[i]);
  __syncthreads();

  // ---- P0: denominators for T0 ----
  float rsum0[2] = {0.f, 0.f};
  int cur = 0;
  for (int kt = 0; kt < 16; ++kt) {
    int nx = ((kt + 1) & 15) * 16384;   // kt=15 wraps: tile 0 ready for P1
#pragma unroll
    for (int i = 0; i < 4; i++)
      gl2lds(ksrc[i] + nx, (char*)sK + (cur ^ 1) * 16384 + ldst[i]);
    const char* kb = (char*)sK + cur * 16384;
#pragma unroll
    for (int nf = 0; nf < 8; nf++) {
      int krow = nf * 16 + lr, sw = (krow & 7) << 4;
      bf16x8 k0 = *(const bf16x8*)(kb + krow * 128 + ((g * 16) ^ sw));
      bf16x8 k1 = *(const bf16x8*)(kb + krow * 128 + ((64 + g * 16) ^ sw));
#pragma unroll
      for (int mi = 0; mi < 2; mi++) {
        f32x4 t = {};
        t = mfma16(k0, qb0[mi][0], t);
        t = mfma16(k1, qb0[mi][1], t);
        rsum0[mi] += __builtin_amdgcn_exp2f(t[0]) + __builtin_amdgcn_exp2f(t[1])
                   + __builtin_amdgcn_exp2f(t[2]) + __builtin_amdgcn_exp2f(t[3]);
      }
    }
    __syncthreads();
    cur ^= 1;
  }
  float lrl0[2];
#pragma unroll
  for (int mi = 0; mi < 2; mi++) {
    float s = rsum0[mi];
    s += __shfl_xor(s, 16); s += __shfl_xor(s, 32);
    lrl0[mi] = -__builtin_amdgcn_logf(s);   // -log2(sum)
  }
  // coalesced-store lane mapping (see R8): instr (mi,h,c): lane l -> row 8h+(l>>3),
  // 16B at k=32c+4(l&7); source lane 8h+(l>>3)+16(l&3); reg w4[2c+((l>>2)&1)]
  const int osrc0 = (lane >> 3) + 16 * (lane & 3);
  const int osrc1 = 8 + (lane >> 3) + 16 * (lane & 3);
  const bool selhi = (lane >> 2) & 1;
  float* wrow0[2][2]; float* wrow1[2][2];
#pragma unroll
  for (int mi = 0; mi < 2; mi++)
#pragma unroll
    for (int h = 0; h < 2; h++) {
      wrow0[mi][h] = Wout + ((size_t)bh * SEQ + qw0 + mi * 16 + 8 * h + (lane >> 3)) * SEQ
                     + 4 * (lane & 7);
      wrow1[mi][h] = Wout + ((size_t)bh * SEQ + qw1 + mi * 16 + 8 * h + (lane >> 3)) * SEQ
                     + 4 * (lane & 7);
    }

  // ---- P1: weights+PV for T0, denominators for T1 (shared K tile) ----
  float rsum1[2] = {0.f, 0.f};
  f32x4 oc0[2][4] = {};
  for (int kt = 0; kt < 16; ++kt) {
#pragma unroll
    for (int i = 0; i < 4; i++) {
      gl2lds(ksrc[i] + ((kt + 1) & 15) * 16384, (char*)sK + (cur ^ 1) * 16384 + ldst[i]);
      gl2lds(vsrc[i] + kt * 256, (char*)sV + ldst[i]);
    }
    const char* kb = (char*)sK + cur * 16384;
#pragma unroll
    for (int mi = 0; mi < 2; mi++) {
      f32x4 wreg[8];
#pragma unroll
      for (int nf = 0; nf < 8; nf++) {
        int krow = nf * 16 + lr, sw = (krow & 7) << 4;
        bf16x8 k0 = *(const bf16x8*)(kb + krow * 128 + ((g * 16) ^ sw));
        bf16x8 k1 = *(const bf16x8*)(kb + krow * 128 + ((64 + g * 16) ^ sw));
        f32x4 t = {};
        t = mfma16(k0, qb0[mi][0], t);
        t = mfma16(k1, qb0[mi][1], t);
        f32x4 w4;
        w4[0] = __builtin_amdgcn_exp2f(t[0] + lrl0[mi]);
        w4[1] = __builtin_amdgcn_exp2f(t[1] + lrl0[mi]);
        w4[2] = __builtin_amdgcn_exp2f(t[2] + lrl0[mi]);
        w4[3] = __builtin_amdgcn_exp2f(t[3] + lrl0[mi]);
        wreg[nf] = w4;
        bf16x4 p4;
        p4[0] = (bf16)w4[0]; p4[1] = (bf16)w4[1]; p4[2] = (bf16)w4[2]; p4[3] = (bf16)w4[3];
        int lq = wv * 32 + mi * 16 + lr;
        *(bf16x4*)((char*)sP + lq * 256 + (((nf * 16 + g * 4) * 2) ^ ((lq & 7) << 4))) = p4;
      }
#pragma unroll
      for (int h = 0; h < 2; h++) {
        int osrc = h ? osrc1 : osrc0;
#pragma unroll
        for (int c = 0; c < 4; c++) {
          f32x4 va, vb, outv;
#pragma unroll
          for (int e = 0; e < 4; e++) {
            va[e] = __shfl(wreg[2 * c][e], osrc);
            vb[e] = __shfl(wreg[2 * c + 1][e], osrc);
          }
#pragma unroll
          for (int e = 0; e < 4; e++) outv[e] = selhi ? vb[e] : va[e];
          __builtin_nontemporal_store(outv,
              (f32x4*)(wrow0[mi][h] + kt * 128 + 32 * c));
        }
      }
    }
    // T1 denominators ride under the store stream (K tile already in LDS)
#pragma unroll
    for (int nf = 0; nf < 8; nf++) {
      int krow = nf * 16 + lr, sw = (krow & 7) << 4;
      bf16x8 k0 = *(const bf16x8*)(kb + krow * 128 + ((g * 16) ^ sw));
      bf16x8 k1 = *(const bf16x8*)(kb + krow * 128 + ((64 + g * 16) ^ sw));
#pragma unroll
      for (int mi = 0; mi < 2; mi++) {
        f32x4 t = {};
        t = mfma16(k0, qb1[mi][0], t);
        t = mfma16(k1, qb1[mi][1], t);
        rsum1[mi] += __builtin_amdgcn_exp2f(t[0]) + __builtin_amdgcn_exp2f(t[1])
                   + __builtin_amdgcn_exp2f(t[2]) + __builtin_amdgcn_exp2f(t[3]);
      }
    }
    BAR_VM16();
#pragma unroll
    for (int c = 0; c < 4; c++) {
      bf16x8 pa[2];
#pragma unroll
      for (int mi = 0; mi < 2; mi++) {
        int lq = wv * 32 + mi * 16 + lr;
        pa[mi] = *(const bf16x8*)((char*)sP + lq * 256 + ((c * 64 + g * 16) ^ ((lq & 7) << 4)));
      }
#pragma unroll
      for (int df = 0; df < 4; df++) {
        int dr = df * 16 + lr;
        bf16x8 vb2 = *(const bf16x8*)((char*)sV + dr * 256 + ((c * 64 + g * 16) ^ ((dr & 7) << 4)));
#pragma unroll
        for (int mi = 0; mi < 2; mi++)
          oc0[mi][df] = mfma16(pa[mi], vb2, oc0[mi][df]);
      }
    }
    BAR_LGKM();
    cur ^= 1;
  }
  float lrl1[2];
#pragma unroll
  for (int mi = 0; mi < 2; mi++) {
    float s = rsum1[mi];
    s += __shfl_xor(s, 16); s += __shfl_xor(s, 32);
    lrl1[mi] = -__builtin_amdgcn_logf(s);
  }
  // write O for T0
  {
    int b = bh >> 4, h = bh & 15;
#pragma unroll
    for (int mi = 0; mi < 2; mi++)
#pragma unroll
      for (int df = 0; df < 4; df++)
#pragma unroll
        for (int r = 0; r < 4; r++) {
          int q = qw0 + mi * 16 + g * 4 + r;
          int dd = df * 16 + lr;
          O[((size_t)(b * SEQ + q) * NH + h) * HD + dd] = (bf16)oc0[mi][df][r];
        }
  }

  // ---- P2: weights+PV for T1 ----
  f32x4 oc1[2][4] = {};
  for (int kt = 0; kt < 16; ++kt) {
#pragma unroll
    for (int i = 0; i < 4; i++) {
      if (kt < 15)
        gl2lds(ksrc[i] + (kt + 1) * 16384, (char*)sK + (cur ^ 1) * 16384 + ldst[i]);
      gl2lds(vsrc[i] + kt * 256, (char*)sV + ldst[i]);
    }
    const char* kb = (char*)sK + cur * 16384;
#pragma unroll
    for (int mi = 0; mi < 2; mi++) {
      f32x4 wreg[8];
#pragma unroll
      for (int nf = 0; nf < 8; nf++) {
        int krow = nf * 16 + lr, sw = (krow & 7) << 4;
        bf16x8 k0 = *(const bf16x8*)(kb + krow * 128 + ((g * 16) ^ sw));
        bf16x8 k1 = *(const bf16x8*)(kb + krow * 128 + ((64 + g * 16) ^ sw));
        f32x4 t = {};
        t = mfma16(k0, qb1[mi][0], t);
        t = mfma16(k1, qb1[mi][1], t);
        f32x4 w4;
        w4[0] = __builtin_amdgcn_exp2f(t[0] + lrl1[mi]);
        w4[1] = __builtin_amdgcn_exp2f(t[1] + lrl1[mi]);
        w4[2] = __builtin_amdgcn_exp2f(t[2] + lrl1[mi]);
        w4[3] = __builtin_amdgcn_exp2f(t[3] + lrl1[mi]);
        wreg[nf] = w4;
        bf16x4 p4;
        p4[0] = (bf16)w4[0]; p4[1] = (bf16)w4[1]; p4[2] = (bf16)w4[2]; p4[3] = (bf16)w4[3];
        int lq = wv * 32 + mi * 16 + lr;
        *(bf16x4*)((char*)sP + lq * 256 + (((nf * 16 + g * 4) * 2) ^ ((lq & 7) << 4))) = p4;
      }
#pragma unroll
      for (int h = 0; h < 2; h++) {
        int osrc = h ? osrc1 : osrc0;
#pragma unroll
        for (int c = 0; c < 4; c++) {
          f32x4 va, vb, outv;
#pragma unroll
          for (int e = 0; e < 4; e++) {
            va[e] = __shfl(wreg[2 * c][e], osrc);
            vb[e] = __shfl(wreg[2 * c + 1][e], osrc);
          }
#pragma unroll
          for (int e = 0; e < 4; e++) outv[e] = selhi ? vb[e] : va[e];
          __builtin_nontemporal_store(outv,
              (f32x4*)(wrow1[mi][h] + kt * 128 + 32 * c));
        }
      }
    }
    BAR_VM16();
#pragma unroll
    for (int c = 0; c < 4; c++) {
      bf16x8 pa[2];
#pragma unroll
      for (int mi = 0; mi < 2; mi++) {
        int lq = wv * 32 + mi * 16 + lr;
        pa[mi] = *(const bf16x8*)((char*)sP + lq * 256 + ((c * 64 + g * 16) ^ ((lq & 7) << 4)));
      }
#pragma unroll
      for (int df = 0; df < 4; df++) {
        int dr = df * 16 + lr;
        bf16x8 vb2 = *(const bf16x8*)((char*)sV + dr * 256 + ((c * 64 + g * 16) ^ ((dr & 7) << 4)));
#pragma unroll
        for (int mi = 0; mi < 2; mi++)
          oc1[mi][df] = mfma16(pa[mi], vb2, oc1[mi][df]);
      }
    }
    BAR_LGKM();
    cur ^= 1;
  }
  {
    int b = bh >> 4, h = bh & 15;
#pragma unroll
    for (int mi = 0; mi < 2; mi++)
#pragma unroll
      for (int df = 0; df < 4; df++)
#pragma unroll
        for (int r = 0; r < 4; r++) {
          int q = qw1 + mi * 16 + g * 4 + r;
          int dd = df * 16 + lr;
          O[((size_t)(b * SEQ + q) * NH + h) * HD + dd] = (bf16)oc1[mi][df][r];
        }
  }
}

extern "C" void kernel_launch(void* const* d_in, const int* in_sizes, int n_in,
                              void* d_out, int out_size, void* d_ws, size_t ws_size,
                              hipStream_t stream) {
  const float* q  = (const float*)d_in[0];
  const float* k  = (const float*)d_in[1];
  const float* v  = (const float*)d_in[2];
  const float* Wq = (const float*)d_in[3];
  const float* bq = (const float*)d_in[4];
  const float* Wk = (const float*)d_in[5];
  const float* bk = (const float*)d_in[6];
  const float* Wv = (const float*)d_in[7];
  const float* bv = (const float*)d_in[8];
  const float* Wo = (const float*)d_in[9];
  const float* bo = (const float*)d_in[10];

  char* ws = (char*)d_ws;
  bf16* Obuf = (bf16*)(ws);                       // attn output (16MB slot)
  bf16* Wt3  = (bf16*)(ws + 16777216);            // WtQ|WtK|WtV contiguous (6MB)
  bf16* WtO  = (bf16*)(ws + 16777216 + 3 * 2097152);
  bf16* HQ   = (bf16*)(ws + 25165824);            // Qh (16MB) then Kh (16MB)
  bf16* Kh   = (bf16*)(ws + 41943040);
  bf16* Vt   = (bf16*)(ws + 75497472);

  float* out0 = (float*)d_out;
  float* wout = out0 + (size_t)M_TOT * D_MODEL;

  dim3 blk(256);
  k_twt<<<dim3(16, 16, 4), blk, 0, stream>>>(Wq, Wk, Wv, Wo,
                                             Wt3, Wt3 + 1048576, Wt3 + 2097152, WtO);
  k_qkv<<<dim3(1536), blk, 0, stream>>>(q, k, v, Wt3, bq, bk, bv, HQ, Vt);
  k_attn<<<dim3(512), blk, 0, stream>>>(HQ, Kh, Vt, wout, Obuf);
  k_ogemm<<<dim3(512), blk, 0, stream>>>(Obuf, WtO, bo, out0);
}

// Round 10
// 347.698 us; speedup vs baseline: 1.0725x; 1.0725x over previous
//
#include <hip/hip_runtime.h>
#include <hip/hip_bf16.h>
#include <stdint.h>

#define D_MODEL 1024
#define NH      16
#define HD      64
#define B_SZ    4
#define SEQ     2048
#define M_TOT   (B_SZ*SEQ)
#define LOG2E_O8 0.18033688011112042f   // log2(e)/8

typedef __bf16 bf16;
typedef bf16  bf16x8 __attribute__((ext_vector_type(8)));
typedef bf16  bf16x4 __attribute__((ext_vector_type(4)));
typedef float f32x4  __attribute__((ext_vector_type(4)));

static __device__ __forceinline__ f32x4 mfma16(bf16x8 a, bf16x8 b, f32x4 c) {
  return __builtin_amdgcn_mfma_f32_16x16x32_bf16(a, b, c, 0, 0, 0);
}

static __device__ __forceinline__ void gl2lds(const void* g, void* l) {
  __builtin_amdgcn_global_load_lds(
      (const __attribute__((address_space(1))) unsigned int*)g,
      (__attribute__((address_space(3))) unsigned int*)l,
      16, 0, 0);
}

#define BAR_VM16() do { \
  asm volatile("s_waitcnt vmcnt(16) lgkmcnt(0)" ::: "memory"); \
  __builtin_amdgcn_s_barrier(); \
  __builtin_amdgcn_sched_barrier(0); \
} while (0)

#define BAR_LGKM() do { \
  asm volatile("s_waitcnt lgkmcnt(0)" ::: "memory"); \
  __builtin_amdgcn_s_barrier(); \
  __builtin_amdgcn_sched_barrier(0); \
} while (0)

// pair-row LDS offset for 32-k (64B) rows: rows packed 2-per-128B, XOR swizzle
// on 16B slots by (pair&7). Same formula for write and read => consistent.
static __device__ __forceinline__ int lds_off(int r, int kb) {
  return ((r >> 1) << 7) + ((((r & 1) << 6) + kb) ^ (((r >> 1) & 7) << 4));
}

// -------- transpose+convert 4 weights: W[k][n] f32 -> Wt[n][k] bf16 --------
__global__ __launch_bounds__(256) void k_twt(const float* __restrict__ w0,
                                             const float* __restrict__ w1,
                                             const float* __restrict__ w2,
                                             const float* __restrict__ w3,
                                             bf16* __restrict__ t0,
                                             bf16* __restrict__ t1,
                                             bf16* __restrict__ t2,
                                             bf16* __restrict__ t3) {
  __shared__ bf16 t[64][65];
  int z = blockIdx.z;
  const float* W = z == 0 ? w0 : z == 1 ? w1 : z == 2 ? w2 : w3;
  bf16* Wt = z == 0 ? t0 : z == 1 ? t1 : z == 2 ? t2 : t3;
  int k0 = blockIdx.x * 64, n0 = blockIdx.y * 64;
  int r = threadIdx.x >> 2, c0 = (threadIdx.x & 3) * 16;
  const float* p = W + (size_t)(k0 + r) * D_MODEL + n0 + c0;
#pragma unroll
  for (int e = 0; e < 16; e += 4) {
    float4 v = *(const float4*)(p + e);
    t[r][c0+e+0] = (bf16)v.x; t[r][c0+e+1] = (bf16)v.y;
    t[r][c0+e+2] = (bf16)v.z; t[r][c0+e+3] = (bf16)v.w;
  }
  __syncthreads();
  bf16x8 o0, o1;
#pragma unroll
  for (int e = 0; e < 8; e++) { o0[e] = t[c0+e][r]; o1[e] = t[c0+8+e][r]; }
  bf16* q = Wt + (size_t)(n0 + r) * D_MODEL + k0 + c0;
  *(bf16x8*)q = o0; *(bf16x8*)(q + 8) = o1;
}

// -------- deep-pipelined QKV GEMM: BM=128 BN=256 BK=32, tri-buffered --------
// One raw barrier per K-step, counted vmcnt(8): next-tile loads span barriers.
// A fp32 reg-staged (issue-early/write-late); B bf16 via gl2lds (pre-swizzled src).
__global__ __launch_bounds__(256, 2) void k_qkv8(const float* __restrict__ Aq,
                                                 const float* __restrict__ Ak,
                                                 const float* __restrict__ Av,
                                                 const bf16* __restrict__ Wt3,
                                                 const float* __restrict__ bq,
                                                 const float* __restrict__ bk,
                                                 const float* __restrict__ bv,
                                                 bf16* __restrict__ HQ,
                                                 bf16* __restrict__ Vt) {
  __shared__ alignas(16) char smem[73728];  // A: 3x8KB @0, B: 3x16KB @24576
  const int tid = threadIdx.x;
  const int lane = tid & 63, wv = tid >> 6;
  const int g = lane >> 4, lr = lane & 15;
  const int wm = wv >> 1, wn = wv & 1;
  const int dd = blockIdx.x;
  const int P = (dd & 7) * 96 + (dd >> 3);       // XCD-affine
  const int seg = P >> 8;
  const int rem = P & 255;
  const int m0 = (rem >> 2) * 128;
  const int n0 = (rem & 3) * 256;

  const float* A = seg == 0 ? Aq : seg == 1 ? Ak : Av;
  const float* bias = seg == 0 ? bq : seg == 1 ? bk : bv;
  const float oscale = seg == 0 ? LOG2E_O8 : 1.0f;

  // A staging: thread t -> row t>>1, 16 fp32 at col (t&1)*16
  const float* aptr = A + (size_t)(m0 + (tid >> 1)) * D_MODEL + (tid & 1) * 16;
  const int awoff0 = lds_off(tid >> 1, (tid & 1) * 32);
  const int awoff1 = lds_off(tid >> 1, (tid & 1) * 32 + 16);
  // B staging: linear dest, inverse-swizzled source
  const char* bsrc[4]; int bdst[4];
#pragma unroll
  for (int u = 0; u < 4; u++) {
    int o = u * 4096 + tid * 16;
    int p = o >> 7, w = o & 127;
    int wq = w ^ ((p & 7) << 4);
    int r = p * 2 + (wq >> 6), kb = wq & 63;
    bsrc[u] = (const char*)(Wt3 + (size_t)(seg * 1024 + n0 + r) * D_MODEL) + kb;
    bdst[u] = o;
  }
  int aoff[4], boff[8];
#pragma unroll
  for (int mi = 0; mi < 4; mi++) aoff[mi] = lds_off(wm * 64 + mi * 16 + lr, g * 16);
#pragma unroll
  for (int ni = 0; ni < 8; ni++) boff[ni] = lds_off(wn * 128 + ni * 16 + lr, g * 16);

  f32x4 acc[4][8] = {};
  float4 af[4];

  // prologue: tile 0
#pragma unroll
  for (int j = 0; j < 4; j++) af[j] = *(const float4*)(aptr + j * 4);
#pragma unroll
  for (int u = 0; u < 4; u++) gl2lds(bsrc[u], smem + 24576 + bdst[u]);
  asm volatile("s_waitcnt vmcnt(0)" ::: "memory");
  {
    bf16x8 w8a, w8b;
#pragma unroll
    for (int e = 0; e < 4; e++) {
      w8a[e] = (bf16)af[0][e]; w8a[4+e] = (bf16)af[1][e];
      w8b[e] = (bf16)af[2][e]; w8b[4+e] = (bf16)af[3][e];
    }
    *(bf16x8*)(smem + awoff0) = w8a;
    *(bf16x8*)(smem + awoff1) = w8b;
  }

  int bufc = 0;
  for (int s = 0; s < 32; ++s) {
    int kn = (s + 1) & 31;                 // s=31 wraps: harmless reload keeps counts
    int nxt = bufc + 1; if (nxt == 3) nxt = 0;
    // issue A(s+1) loads (oldest), then B(s+1) gl2lds
#pragma unroll
    for (int j = 0; j < 4; j++) af[j] = *(const float4*)(aptr + kn * 32 + j * 4);
#pragma unroll
    for (int u = 0; u < 4; u++)
      gl2lds(bsrc[u] + kn * 64, smem + 24576 + nxt * 16384 + bdst[u]);
    // drain B(s) (4 oldest of 12) + prior ds_writes; keep 8 in flight
    asm volatile("s_waitcnt vmcnt(8) lgkmcnt(0)" ::: "memory");
    __builtin_amdgcn_s_barrier();
    __builtin_amdgcn_sched_barrier(0);
    const char* bA = smem + bufc * 8192;
    const char* bB = smem + 24576 + bufc * 16384;
    bf16x8 a[4], b[8];
#pragma unroll
    for (int mi = 0; mi < 4; mi++) a[mi] = *(const bf16x8*)(bA + aoff[mi]);
#pragma unroll
    for (int ni = 0; ni < 8; ni++) b[ni] = *(const bf16x8*)(bB + boff[ni]);
#pragma unroll
    for (int mi = 0; mi < 4; mi++)
#pragma unroll
      for (int ni = 0; ni < 8; ni++)
        acc[mi][ni] = mfma16(a[mi], b[ni], acc[mi][ni]);
    // write A(s+1) (compiler waits af's own vmcnt)
    {
      bf16x8 w8a, w8b;
#pragma unroll
      for (int e = 0; e < 4; e++) {
        w8a[e] = (bf16)af[0][e]; w8a[4+e] = (bf16)af[1][e];
        w8b[e] = (bf16)af[2][e]; w8b[4+e] = (bf16)af[3][e];
      }
      *(bf16x8*)(smem + nxt * 8192 + awoff0) = w8a;
      *(bf16x8*)(smem + nxt * 8192 + awoff1) = w8b;
    }
    bufc = nxt;
  }

  if (seg < 2) {
    bf16* outp = HQ + (size_t)seg * 8388608;
#pragma unroll
    for (int mi = 0; mi < 4; mi++) {
#pragma unroll
      for (int ni = 0; ni < 8; ni++) {
        int n = n0 + wn * 128 + ni * 16 + lr;
        float bvl = bias[n];
        int h = n >> 6, dcol = n & 63;
#pragma unroll
        for (int r = 0; r < 4; r++) {
          int m = m0 + wm * 64 + mi * 16 + g * 4 + r;
          int b2 = m >> 11, q = m & 2047;
          outp[(((size_t)(b2 * NH + h)) * SEQ + q) * HD + dcol] =
              (bf16)((acc[mi][ni][r] + bvl) * oscale);
        }
      }
    }
  } else {
    // V: transpose 256n x 128m in LDS (64KB, reuses smem), write Vt[bh][d][q]
    __syncthreads();
    char* tr = smem;
#pragma unroll
    for (int mi = 0; mi < 4; mi++) {
#pragma unroll
      for (int ni = 0; ni < 8; ni++) {
        int n_loc = wn * 128 + ni * 16 + lr;
        float bvl = bias[n0 + n_loc];
        bf16x4 pq;
#pragma unroll
        for (int r = 0; r < 4; r++) pq[r] = (bf16)(acc[mi][ni][r] + bvl);
        int m0l = wm * 64 + mi * 16 + g * 4;
        *(bf16x4*)(tr + n_loc * 256 + ((m0l * 2) ^ ((n_loc & 7) << 4))) = pq;
      }
    }
    __syncthreads();
    int n_loc = tid;
    int n_glob = n0 + n_loc;
    int h = n_glob >> 6, dcol = n_glob & 63;
    int b2 = m0 >> 11, q0l = m0 & 2047;
    bf16* vp = Vt + ((size_t)(b2 * NH + h) * HD + dcol) * SEQ + q0l;
    int sw = (n_loc & 7) << 4;
#pragma unroll
    for (int c = 0; c < 16; c++) {
      bf16x8 v8 = *(const bf16x8*)(tr + n_loc * 256 + ((c * 16) ^ sw));
      *(bf16x8*)(vp + c * 8) = v8;
    }
  }
}

// -------- O-projection GEMM: A bf16 via gl2lds, out f32 [M,1024] --------
__global__ __launch_bounds__(256) void k_ogemm(const bf16* __restrict__ A,
                                               const bf16* __restrict__ Bt,
                                               const float* __restrict__ bias,
                                               float* __restrict__ outp) {
  __shared__ alignas(16) bf16 sA[2][8192];
  __shared__ alignas(16) bf16 sB[2][8192];
  const int tid = threadIdx.x;
  const int lane = tid & 63, wv = tid >> 6;
  const int g = lane >> 4, lr = lane & 15;
  const int wm = wv >> 1, wn = wv & 1;
  const int d = blockIdx.x;
  const int m0 = ((d & 7) * 8 + (d >> 6)) * 128;
  const int n0 = ((d >> 3) & 7) * 128;

  const char* asrc[4]; const char* bsrc[4]; int dst[4];
#pragma unroll
  for (int i = 0; i < 4; i++) {
    int o = i * 4096 + tid * 16;
    int row = o >> 7, in = o & 127;
    int cs = in ^ ((row & 7) << 4);
    asrc[i] = (const char*)A  + (size_t)(m0 + row) * 2048 + cs;
    bsrc[i] = (const char*)Bt + (size_t)(n0 + row) * 2048 + cs;
    dst[i] = i * 4096 + wv * 1024;
  }
  int fa[4], fb[4], swa[4], swb[4];
#pragma unroll
  for (int i = 0; i < 4; i++) {
    int rowa = wm * 64 + i * 16 + lr;
    int rowb = wn * 64 + i * 16 + lr;
    fa[i] = rowa * 128; swa[i] = (rowa & 7) << 4;
    fb[i] = rowb * 128; swb[i] = (rowb & 7) << 4;
  }
  f32x4 acc[4][4] = {};
#pragma unroll
  for (int i = 0; i < 4; i++) {
    gl2lds(asrc[i], (char*)sA[0] + dst[i]);
    gl2lds(bsrc[i], (char*)sB[0] + dst[i]);
  }
  __syncthreads();
  int cur = 0;
  for (int kt = 0; kt < 16; ++kt) {
    if (kt < 15) {
#pragma unroll
      for (int i = 0; i < 4; i++) {
        gl2lds(asrc[i] + (kt + 1) * 128, (char*)sA[cur ^ 1] + dst[i]);
        gl2lds(bsrc[i] + (kt + 1) * 128, (char*)sB[cur ^ 1] + dst[i]);
      }
    }
    const char* bA = (const char*)sA[cur];
    const char* bB = (const char*)sB[cur];
#pragma unroll
    for (int c = 0; c < 2; c++) {
      bf16x8 a[4], b[4];
      int off = c * 64 + g * 16;
#pragma unroll
      for (int i = 0; i < 4; i++) {
        a[i] = *(const bf16x8*)(bA + fa[i] + (off ^ swa[i]));
        b[i] = *(const bf16x8*)(bB + fb[i] + (off ^ swb[i]));
      }
#pragma unroll
      for (int mi = 0; mi < 4; mi++)
#pragma unroll
        for (int ni = 0; ni < 4; ni++)
          acc[mi][ni] = mfma16(a[mi], b[ni], acc[mi][ni]);
    }
    __syncthreads();
    cur ^= 1;
  }
#pragma unroll
  for (int mi = 0; mi < 4; mi++) {
#pragma unroll
    for (int ni = 0; ni < 4; ni++) {
      int n = n0 + wn * 64 + ni * 16 + lr;
      float bvl = bias[n];
#pragma unroll
      for (int r = 0; r < 4; r++) {
        int m = m0 + wm * 64 + mi * 16 + g * 4 + r;
        outp[(size_t)m * D_MODEL + n] = acc[mi][ni][r] + bvl;
      }
    }
  }
}

// -------- fused attention: 2-tile pipelined, swapped QK^T (exp2), coalesced NT W --------
__global__ __launch_bounds__(256) void k_attn(const bf16* __restrict__ Qh,
                                              const bf16* __restrict__ Kh,
                                              const bf16* __restrict__ Vt,
                                              float* __restrict__ Wout,
                                              bf16* __restrict__ O) {
  __shared__ alignas(16) bf16 sK[2][8192];
  __shared__ alignas(16) bf16 sV[8192];
  __shared__ alignas(16) bf16 sP[16384];
  const int tid = threadIdx.x, lane = tid & 63, wv = tid >> 6;
  const int g = lane >> 4, lr = lane & 15;
  int swzb = (blockIdx.x & 7) * 64 + (blockIdx.x >> 3);
  const int bh = swzb >> 3;
  const int qt0 = (swzb & 7) * 256;
  const int qw0 = qt0 + wv * 32;
  const int qw1 = qt0 + 128 + wv * 32;

  bf16x8 qb0[2][2], qb1[2][2];
#pragma unroll
  for (int mi = 0; mi < 2; mi++)
#pragma unroll
    for (int c = 0; c < 2; c++) {
      qb0[mi][c] = *(const bf16x8*)(Qh + ((size_t)bh * SEQ + qw0 + mi * 16 + lr) * HD + c * 32 + g * 8);
      qb1[mi][c] = *(const bf16x8*)(Qh + ((size_t)bh * SEQ + qw1 + mi * 16 + lr) * HD + c * 32 + g * 8);
    }

  const char* kbase = (const char*)(Kh + (size_t)bh * SEQ * HD);
  const char* vbase = (const char*)(Vt + (size_t)bh * HD * SEQ);
  const char* ksrc[4]; const char* vsrc[4]; int ldst[4];
#pragma unroll
  for (int i = 0; i < 4; i++) {
    int o = i * 4096 + tid * 16;
    int kr = o >> 7, kin = o & 127;
    ksrc[i] = kbase + (size_t)kr * 128 + (kin ^ ((kr & 7) << 4));
    int dr = o >> 8, vin = o & 255;
    vsrc[i] = vbase + (size_t)dr * 4096 + (vin ^ ((dr & 7) << 4));
    ldst[i] = i * 4096 + wv * 1024;
  }

#pragma unroll
  for (int i = 0; i < 4; i++) gl2lds(ksrc[i], (char*)sK + ldst[i]);
  __syncthreads();

  float rsum0[2] = {0.f, 0.f};
  int cur = 0;
  for (int kt = 0; kt < 16; ++kt) {
    int nx = ((kt + 1) & 15) * 16384;
#pragma unroll
    for (int i = 0; i < 4; i++)
      gl2lds(ksrc[i] + nx, (char*)sK + (cur ^ 1) * 16384 + ldst[i]);
    const char* kb = (char*)sK + cur * 16384;
#pragma unroll
    for (int nf = 0; nf < 8; nf++) {
      int krow = nf * 16 + lr, sw = (krow & 7) << 4;
      bf16x8 k0 = *(const bf16x8*)(kb + krow * 128 + ((g * 16) ^ sw));
      bf16x8 k1 = *(const bf16x8*)(kb + krow * 128 + ((64 + g * 16) ^ sw));
#pragma unroll
      for (int mi = 0; mi < 2; mi++) {
        f32x4 t = {};
        t = mfma16(k0, qb0[mi][0], t);
        t = mfma16(k1, qb0[mi][1], t);
        rsum0[mi] += __builtin_amdgcn_exp2f(t[0]) + __builtin_amdgcn_exp2f(t[1])
                   + __builtin_amdgcn_exp2f(t[2]) + __builtin_amdgcn_exp2f(t[3]);
      }
    }
    __syncthreads();
    cur ^= 1;
  }
  float lrl0[2];
#pragma unroll
  for (int mi = 0; mi < 2; mi++) {
    float s = rsum0[mi];
    s += __shfl_xor(s, 16); s += __shfl_xor(s, 32);
    lrl0[mi] = -__builtin_amdgcn_logf(s);
  }
  const int osrc0 = (lane >> 3) + 16 * (lane & 3);
  const int osrc1 = 8 + (lane >> 3) + 16 * (lane & 3);
  const bool selhi = (lane >> 2) & 1;
  float* wrow0[2][2]; float* wrow1[2][2];
#pragma unroll
  for (int mi = 0; mi < 2; mi++)
#pragma unroll
    for (int h = 0; h < 2; h++) {
      wrow0[mi][h] = Wout + ((size_t)bh * SEQ + qw0 + mi * 16 + 8 * h + (lane >> 3)) * SEQ
                     + 4 * (lane & 7);
      wrow1[mi][h] = Wout + ((size_t)bh * SEQ + qw1 + mi * 16 + 8 * h + (lane >> 3)) * SEQ
                     + 4 * (lane & 7);
    }

  float rsum1[2] = {0.f, 0.f};
  f32x4 oc0[2][4] = {};
  for (int kt = 0; kt < 16; ++kt) {
#pragma unroll
    for (int i = 0; i < 4; i++) {
      gl2lds(ksrc[i] + ((kt + 1) & 15) * 16384, (char*)sK + (cur ^ 1) * 16384 + ldst[i]);
      gl2lds(vsrc[i] + kt * 256, (char*)sV + ldst[i]);
    }
    const char* kb = (char*)sK + cur * 16384;
#pragma unroll
    for (int mi = 0; mi < 2; mi++) {
      f32x4 wreg[8];
#pragma unroll
      for (int nf = 0; nf < 8; nf++) {
        int krow = nf * 16 + lr, sw = (krow & 7) << 4;
        bf16x8 k0 = *(const bf16x8*)(kb + krow * 128 + ((g * 16) ^ sw));
        bf16x8 k1 = *(const bf16x8*)(kb + krow * 128 + ((64 + g * 16) ^ sw));
        f32x4 t = {};
        t = mfma16(k0, qb0[mi][0], t);
        t = mfma16(k1, qb0[mi][1], t);
        f32x4 w4;
        w4[0] = __builtin_amdgcn_exp2f(t[0] + lrl0[mi]);
        w4[1] = __builtin_amdgcn_exp2f(t[1] + lrl0[mi]);
        w4[2] = __builtin_amdgcn_exp2f(t[2] + lrl0[mi]);
        w4[3] = __builtin_amdgcn_exp2f(t[3] + lrl0[mi]);
        wreg[nf] = w4;
        bf16x4 p4;
        p4[0] = (bf16)w4[0]; p4[1] = (bf16)w4[1]; p4[2] = (bf16)w4[2]; p4[3] = (bf16)w4[3];
        int lq = wv * 32 + mi * 16 + lr;
        *(bf16x4*)((char*)sP + lq * 256 + (((nf * 16 + g * 4) * 2) ^ ((lq & 7) << 4))) = p4;
      }
#pragma unroll
      for (int h = 0; h < 2; h++) {
        int osrc = h ? osrc1 : osrc0;
#pragma unroll
        for (int c = 0; c < 4; c++) {
          f32x4 va, vb, outv;
#pragma unroll
          for (int e = 0; e < 4; e++) {
            va[e] = __shfl(wreg[2 * c][e], osrc);
            vb[e] = __shfl(wreg[2 * c + 1][e], osrc);
          }
#pragma unroll
          for (int e = 0; e < 4; e++) outv[e] = selhi ? vb[e] : va[e];
          __builtin_nontemporal_store(outv,
              (f32x4*)(wrow0[mi][h] + kt * 128 + 32 * c));
        }
      }
    }
#pragma unroll
    for (int nf = 0; nf < 8; nf++) {
      int krow = nf * 16 + lr, sw = (krow & 7) << 4;
      bf16x8 k0 = *(const bf16x8*)(kb + krow * 128 + ((g * 16) ^ sw));
      bf16x8 k1 = *(const bf16x8*)(kb + krow * 128 + ((64 + g * 16) ^ sw));
#pragma unroll
      for (int mi = 0; mi < 2; mi++) {
        f32x4 t = {};
        t = mfma16(k0, qb1[mi][0], t);
        t = mfma16(k1, qb1[mi][1], t);
        rsum1[mi] += __builtin_amdgcn_exp2f(t[0]) + __builtin_amdgcn_exp2f(t[1])
                   + __builtin_amdgcn_exp2f(t[2]) + __builtin_amdgcn_exp2f(t[3]);
      }
    }
    BAR_VM16();
#pragma unroll
    for (int c = 0; c < 4; c++) {
      bf16x8 pa[2];
#pragma unroll
      for (int mi = 0; mi < 2; mi++) {
        int lq = wv * 32 + mi * 16 + lr;
        pa[mi] = *(const bf16x8*)((char*)sP + lq * 256 + ((c * 64 + g * 16) ^ ((lq & 7) << 4)));
      }
#pragma unroll
      for (int df = 0; df < 4; df++) {
        int dr = df * 16 + lr;
        bf16x8 vb2 = *(const bf16x8*)((char*)sV + dr * 256 + ((c * 64 + g * 16) ^ ((dr & 7) << 4)));
#pragma unroll
        for (int mi = 0; mi < 2; mi++)
          oc0[mi][df] = mfma16(pa[mi], vb2, oc0[mi][df]);
      }
    }
    BAR_LGKM();
    cur ^= 1;
  }
  float lrl1[2];
#pragma unroll
  for (int mi = 0; mi < 2; mi++) {
    float s = rsum1[mi];
    s += __shfl_xor(s, 16); s += __shfl_xor(s, 32);
    lrl1[mi] = -__builtin_amdgcn_logf(s);
  }
  {
    int b = bh >> 4, h = bh & 15;
#pragma unroll
    for (int mi = 0; mi < 2; mi++)
#pragma unroll
      for (int df = 0; df < 4; df++)
#pragma unroll
        for (int r = 0; r < 4; r++) {
          int q = qw0 + mi * 16 + g * 4 + r;
          int dcol = df * 16 + lr;
          O[((size_t)(b * SEQ + q) * NH + h) * HD + dcol] = (bf16)oc0[mi][df][r];
        }
  }

  f32x4 oc1[2][4] = {};
  for (int kt = 0; kt < 16; ++kt) {
#pragma unroll
    for (int i = 0; i < 4; i++) {
      if (kt < 15)
        gl2lds(ksrc[i] + (kt + 1) * 16384, (char*)sK + (cur ^ 1) * 16384 + ldst[i]);
      gl2lds(vsrc[i] + kt * 256, (char*)sV + ldst[i]);
    }
    const char* kb = (char*)sK + cur * 16384;
#pragma unroll
    for (int mi = 0; mi < 2; mi++) {
      f32x4 wreg[8];
#pragma unroll
      for (int nf = 0; nf < 8; nf++) {
        int krow = nf * 16 + lr, sw = (krow & 7) << 4;
        bf16x8 k0 = *(const bf16x8*)(kb + krow * 128 + ((g * 16) ^ sw));
        bf16x8 k1 = *(const bf16x8*)(kb + krow * 128 + ((64 + g * 16) ^ sw));
        f32x4 t = {};
        t = mfma16(k0, qb1[mi][0], t);
        t = mfma16(k1, qb1[mi][1], t);
        f32x4 w4;
        w4[0] = __builtin_amdgcn_exp2f(t[0] + lrl1[mi]);
        w4[1] = __builtin_amdgcn_exp2f(t[1] + lrl1[mi]);
        w4[2] = __builtin_amdgcn_exp2f(t[2] + lrl1[mi]);
        w4[3] = __builtin_amdgcn_exp2f(t[3] + lrl1[mi]);
        wreg[nf] = w4;
        bf16x4 p4;
        p4[0] = (bf16)w4[0]; p4[1] = (bf16)w4[1]; p4[2] = (bf16)w4[2]; p4[3] = (bf16)w4[3];
        int lq = wv * 32 + mi * 16 + lr;
        *(bf16x4*)((char*)sP + lq * 256 + (((nf * 16 + g * 4) * 2) ^ ((lq & 7) << 4))) = p4;
      }
#pragma unroll
      for (int h = 0; h < 2; h++) {
        int osrc = h ? osrc1 : osrc0;
#pragma unroll
        for (int c = 0; c < 4; c++) {
          f32x4 va, vb, outv;
#pragma unroll
          for (int e = 0; e < 4; e++) {
            va[e] = __shfl(wreg[2 * c][e], osrc);
            vb[e] = __shfl(wreg[2 * c + 1][e], osrc);
          }
#pragma unroll
          for (int e = 0; e < 4; e++) outv[e] = selhi ? vb[e] : va[e];
          __builtin_nontemporal_store(outv,
              (f32x4*)(wrow1[mi][h] + kt * 128 + 32 * c));
        }
      }
    }
    BAR_VM16();
#pragma unroll
    for (int c = 0; c < 4; c++) {
      bf16x8 pa[2];
#pragma unroll
      for (int mi = 0; mi < 2; mi++) {
        int lq = wv * 32 + mi * 16 + lr;
        pa[mi] = *(const bf16x8*)((char*)sP + lq * 256 + ((c * 64 + g * 16) ^ ((lq & 7) << 4)));
      }
#pragma unroll
      for (int df = 0; df < 4; df++) {
        int dr = df * 16 + lr;
        bf16x8 vb2 = *(const bf16x8*)((char*)sV + dr * 256 + ((c * 64 + g * 16) ^ ((dr & 7) << 4)));
#pragma unroll
        for (int mi = 0; mi < 2; mi++)
          oc1[mi][df] = mfma16(pa[mi], vb2, oc1[mi][df]);
      }
    }
    BAR_LGKM();
    cur ^= 1;
  }
  {
    int b = bh >> 4, h = bh & 15;
#pragma unroll
    for (int mi = 0; mi < 2; mi++)
#pragma unroll
      for (int df = 0; df < 4; df++)
#pragma unroll
        for (int r = 0; r < 4; r++) {
          int q = qw1 + mi * 16 + g * 4 + r;
          int dcol = df * 16 + lr;
          O[((size_t)(b * SEQ + q) * NH + h) * HD + dcol] = (bf16)oc1[mi][df][r];
        }
  }
}

extern "C" void kernel_launch(void* const* d_in, const int* in_sizes, int n_in,
                              void* d_out, int out_size, void* d_ws, size_t ws_size,
                              hipStream_t stream) {
  const float* q  = (const float*)d_in[0];
  const float* k  = (const float*)d_in[1];
  const float* v  = (const float*)d_in[2];
  const float* Wq = (const float*)d_in[3];
  const float* bq = (const float*)d_in[4];
  const float* Wk = (const float*)d_in[5];
  const float* bk = (const float*)d_in[6];
  const float* Wv = (const float*)d_in[7];
  const float* bv = (const float*)d_in[8];
  const float* Wo = (const float*)d_in[9];
  const float* bo = (const float*)d_in[10];

  char* ws = (char*)d_ws;
  bf16* Obuf = (bf16*)(ws);
  bf16* Wt3  = (bf16*)(ws + 16777216);
  bf16* WtO  = (bf16*)(ws + 16777216 + 3 * 2097152);
  bf16* HQ   = (bf16*)(ws + 25165824);
  bf16* Kh   = (bf16*)(ws + 41943040);
  bf16* Vt   = (bf16*)(ws + 75497472);

  float* out0 = (float*)d_out;
  float* wout = out0 + (size_t)M_TOT * D_MODEL;

  dim3 blk(256);
  k_twt<<<dim3(16, 16, 4), blk, 0, stream>>>(Wq, Wk, Wv, Wo,
                                             Wt3, Wt3 + 1048576, Wt3 + 2097152, WtO);
  k_qkv8<<<dim3(768), blk, 0, stream>>>(q, k, v, Wt3, bq, bk, bv, HQ, Vt);
  k_attn<<<dim3(512), blk, 0, stream>>>(HQ, Kh, Vt, wout, Obuf);
  k_ogemm<<<dim3(512), blk, 0, stream>>>(Obuf, WtO, bo, out0);
}